// Round 1
// 148.887 us; speedup vs baseline: 1.0611x; 1.0611x over previous
//
#include <hip/hip_runtime.h>
#include <math.h>

// Problem constants: B=4, S=2048, DIN=1024, DOUT=1024, E=16, K=2
#define DIN_  1024
#define DOUT_ 1024
#define NE    16
#define KK    2
#define NTOK  8192
#define RS4   257   // padded LDS row stride in float4 units (1028 floats; +4-float pad kills 16-way bank conflicts)

// ws layout: [0, 128KB): float wc[E][K][DIN] compact expert columns

// ---------------------------------------------------------------------------
// Kernel A: compact expert_w columns j=0,1 into wc[e][j][d].
// float2 load per (e,d): both columns in one 8B load -> each 64B row-head
// line fetched once instead of twice. 16384 threads.
// ---------------------------------------------------------------------------
__global__ __launch_bounds__(256) void compact_w_kernel(
    const float* __restrict__ ew,   // [E, DIN, DOUT]
    float* __restrict__ wc)         // [E, K, DIN]
{
    int i = blockIdx.x * 256 + threadIdx.x;   // over NE*DIN = 16384
    if (i >= NE * DIN_) return;
    int d = i & (DIN_ - 1);
    int e = i >> 10;
    const float2 v = *(const float2*)(ew + (size_t)e * DIN_ * DOUT_ + (size_t)d * DOUT_);
    wc[(size_t)e * KK * DIN_ + d]        = v.x;   // column j=0
    wc[(size_t)e * KK * DIN_ + DIN_ + d] = v.y;   // column j=1
}

// ---------------------------------------------------------------------------
// Fused gate + expert kernel. 512 blocks x 256 threads, 16 tokens/block.
// Phase 1: stage 16 token rows (64KB contiguous) into padded LDS (coalesced).
// Phase 2: gate dots from LDS; in-wave shfl_xor reduce over segments;
//          small cross-wave LDS reduce; sigmoid; top-2; weights -> recs[] LDS.
// Phase 3: wave-per-token expert dots from LDS x + L2-hot wc; broadcast store.
// x is read from HBM exactly once.
// ---------------------------------------------------------------------------
__global__ __launch_bounds__(256) void fused_kernel(
    const float* __restrict__ x,        // [NTOK, DIN]
    const float* __restrict__ gate_w,   // [DIN, E]
    const float* __restrict__ gate_b,   // [E]
    const float* __restrict__ ebias,    // [E]
    const float* __restrict__ wc,       // [E, K, DIN]
    const float* __restrict__ expert_b, // [E, DOUT]
    float* __restrict__ out_final,      // [NTOK, DOUT]
    float* __restrict__ out_probs,      // [NTOK, E]
    float* __restrict__ out_idx,        // [NTOK, K] as float
    int write_aux)
{
    __shared__ float4 xs[16 * RS4];     // 65.8 KB padded x tile
    __shared__ float red2[4][16][17];   // [wave][tok][e] 4.35 KB
    __shared__ float lgt[16][17];       // [tok][e] logits (pre-ebias)
    __shared__ float4 recs[16];         // (e0, e1, w0, w1) per token

    const int tid  = threadIdx.x;
    const int wave = tid >> 6;
    const int lane = tid & 63;
    const int blk  = blockIdx.x;

    // ---- Phase 1: stage x tile (16 rows = 4096 float4, contiguous) ----
    const float4* xg = (const float4*)(x + (size_t)blk * 16 * DIN_);
#pragma unroll
    for (int k = 0; k < 16; k++) {
        int g = k * 256 + tid;                       // 0..4095, coalesced
        xs[(g >> 8) * RS4 + (g & 255)] = xg[g];
    }
    __syncthreads();

    // ---- Phase 2: gate dots. seg-major: token's 4 in-wave segs reduce via shfl ----
    const int seg = tid >> 4;           // 0..15 (wave w owns segs 4w..4w+3)
    const int tok = tid & 15;           // 0..15
    const float4* xrow = xs + tok * RS4 + seg * 16;
    const float4* gw4  = (const float4*)gate_w;      // row d = 4 float4s

    float acc[NE];
#pragma unroll
    for (int e = 0; e < NE; e++) acc[e] = 0.f;

    for (int i = 0; i < 16; i++) {
        float4 xv = xrow[i];
        int d0 = seg * 64 + i * 4;
#pragma unroll
        for (int j = 0; j < 4; j++) {
            int d = d0 + j;
            float xs_ = (j == 0) ? xv.x : (j == 1) ? xv.y : (j == 2) ? xv.z : xv.w;
            float4 g0 = gw4[d * 4 + 0];
            float4 g1 = gw4[d * 4 + 1];
            float4 g2 = gw4[d * 4 + 2];
            float4 g3 = gw4[d * 4 + 3];
            acc[0]  += xs_ * g0.x; acc[1]  += xs_ * g0.y; acc[2]  += xs_ * g0.z; acc[3]  += xs_ * g0.w;
            acc[4]  += xs_ * g1.x; acc[5]  += xs_ * g1.y; acc[6]  += xs_ * g1.z; acc[7]  += xs_ * g1.w;
            acc[8]  += xs_ * g2.x; acc[9]  += xs_ * g2.y; acc[10] += xs_ * g2.z; acc[11] += xs_ * g2.w;
            acc[12] += xs_ * g3.x; acc[13] += xs_ * g3.y; acc[14] += xs_ * g3.z; acc[15] += xs_ * g3.w;
        }
    }

    // in-wave reduce over the wave's 4 segments (lane^16 flips seg bit0, ^32 bit1)
#pragma unroll
    for (int e = 0; e < NE; e++) {
        acc[e] += __shfl_xor(acc[e], 16);
        acc[e] += __shfl_xor(acc[e], 32);
    }
    // one writer per (wave, tok, e): seg&3 group q writes experts 4q..4q+3
    {
        const int q = seg & 3;
#pragma unroll
        for (int j = 0; j < 4; j++) {
            int e = q * 4 + j;
            red2[wave][tok][e] = acc[e];
        }
    }
    __syncthreads();

    // cross-wave reduce + sigmoid + probs write: thread = (rtok, e)
    {
        const int rtok = tid >> 4;
        const int e    = tid & 15;
        float s = red2[0][rtok][e] + red2[1][rtok][e]
                + red2[2][rtok][e] + red2[3][rtok][e] + gate_b[e];
        if (write_aux)
            out_probs[(size_t)(blk * 16 + rtok) * NE + e] = 1.f / (1.f + expf(-s));
        lgt[rtok][e] = s;
    }
    __syncthreads();

    // top-2 + normalized weights: threads 0..15, one token each
    if (tid < 16) {
        const int ftok = tid;
        const int gtoken = blk * 16 + ftok;
        float go[NE], logit[NE];
#pragma unroll
        for (int e = 0; e < NE; e++) {
            go[e] = lgt[ftok][e];
            logit[e] = go[e] + ebias[e];
        }
        // stable top-2 (descending; ties -> lower index)
        int i0 = 0;
        for (int e = 1; e < NE; e++) if (logit[e] > logit[i0]) i0 = e;
        int i1 = -1;
        for (int e = 0; e < NE; e++) {
            if (e == i0) continue;
            if (i1 < 0 || logit[e] > logit[i1]) i1 = e;
        }
        float p0 = 1.f / (1.f + expf(-go[i0]));
        float p1 = 1.f / (1.f + expf(-go[i1]));
        float inv = 1.f / (p0 + p1);
        if (write_aux) {
            out_idx[(size_t)gtoken * KK + 0] = (float)i0;
            out_idx[(size_t)gtoken * KK + 1] = (float)i1;
        }
        recs[ftok] = make_float4((float)i0, (float)i1, p0 * inv, p1 * inv);
    }
    __syncthreads();

    // ---- Phase 3: expert dots + broadcast store. Wave w -> tokens 4w..4w+3 ----
#pragma unroll
    for (int it = 0; it < 4; it++) {
        const int lt = wave * 4 + it;
        float4 rec = recs[lt];                       // uniform broadcast read
        int e0 = (int)rec.x;
        int e1 = (int)rec.y;
        const float4* xr = xs + lt * RS4;
        const float4* w0 = (const float4*)(wc + ((size_t)e0 * KK + 0) * DIN_);
        const float4* w1 = (const float4*)(wc + ((size_t)e1 * KK + 1) * DIN_);
        float g0 = 0.f, g1 = 0.f;
#pragma unroll
        for (int i = 0; i < 4; i++) {
            float4 xv = xr[i * 64 + lane];
            float4 a  = w0[i * 64 + lane];
            float4 b  = w1[i * 64 + lane];
            g0 += xv.x * a.x + xv.y * a.y + xv.z * a.z + xv.w * a.w;
            g1 += xv.x * b.x + xv.y * b.y + xv.z * b.z + xv.w * b.w;
        }
#pragma unroll
        for (int m = 32; m >= 1; m >>= 1) {
            g0 += __shfl_xor(g0, m);
            g1 += __shfl_xor(g1, m);
        }
        float f = rec.z * (g0 + expert_b[(size_t)e0 * DOUT_ + 0])
                + rec.w * (g1 + expert_b[(size_t)e1 * DOUT_ + 1]);
        float4 fv = make_float4(f, f, f, f);
        float4* o4 = (float4*)(out_final + (size_t)(blk * 16 + lt) * DOUT_);
#pragma unroll
        for (int i = 0; i < 4; i++) o4[i * 64 + lane] = fv;
    }
}

// ---------------------------------------------------------------------------
extern "C" void kernel_launch(void* const* d_in, const int* in_sizes, int n_in,
                              void* d_out, int out_size, void* d_ws, size_t ws_size,
                              hipStream_t stream) {
    const float* x        = (const float*)d_in[0];
    const float* gate_w   = (const float*)d_in[1];
    const float* gate_b   = (const float*)d_in[2];
    const float* expert_w = (const float*)d_in[3];
    const float* expert_b = (const float*)d_in[4];
    const float* ebias    = (const float*)d_in[5];
    float* out = (float*)d_out;

    float* wc = (float*)d_ws;                             // 128 KB

    float* out_final = out;
    float* out_probs = out + (size_t)NTOK * DOUT_;
    float* out_idx   = out_probs + (size_t)NTOK * NE;
    int write_aux = (out_size >= NTOK * DOUT_ + NTOK * NE + NTOK * KK) ? 1 : 0;

    compact_w_kernel<<<(NE * DIN_ + 255) / 256, 256, 0, stream>>>(expert_w, wc);
    fused_kernel<<<NTOK / 16, 256, 0, stream>>>(
        x, gate_w, gate_b, ebias, wc, expert_b,
        out_final, out_probs, out_idx, write_aux);
}

// Round 5
// 146.679 us; speedup vs baseline: 1.0770x; 1.0151x over previous
//
#include <hip/hip_runtime.h>
#include <math.h>

// Problem constants: B=4, S=2048, DIN=1024, DOUT=1024, E=16, K=2
#define DIN_  1024
#define DOUT_ 1024
#define NE    16
#define KK    2
#define NTOK  8192
#define TPB   8     // tokens per block
#define RS4   257   // padded LDS row stride in float4 units (1028 floats)

// native vector types for __builtin_nontemporal_* (HIP_vector_type is rejected)
typedef float nf2 __attribute__((ext_vector_type(2)));
typedef float nf4 __attribute__((ext_vector_type(4)));

// ws layout: [0, 128KB): float wc[E][K][DIN] compact expert columns

// ---------------------------------------------------------------------------
// Kernel A: compact expert_w columns j=0,1 into wc[e][j][d].
// nf2 load per (e,d): both columns in one 8B load -> each 64B row-head
// line fetched once. 16384 threads.
// ---------------------------------------------------------------------------
__global__ __launch_bounds__(256) void compact_w_kernel(
    const float* __restrict__ ew,   // [E, DIN, DOUT]
    float* __restrict__ wc)         // [E, K, DIN]
{
    int i = blockIdx.x * 256 + threadIdx.x;   // over NE*DIN = 16384
    if (i >= NE * DIN_) return;
    int d = i & (DIN_ - 1);
    int e = i >> 10;
    const nf2 v = __builtin_nontemporal_load(
        (const nf2*)(ew + (size_t)e * DIN_ * DOUT_ + (size_t)d * DOUT_));
    wc[(size_t)e * KK * DIN_ + d]        = v.x;   // column j=0
    wc[(size_t)e * KK * DIN_ + DIN_ + d] = v.y;   // column j=1
}

// ---------------------------------------------------------------------------
// Fused gate + expert kernel. 1024 blocks x 256 threads, 8 tokens/block.
// LDS ~36 KB -> 4 blocks/CU (16 waves/CU) for cross-block phase overlap.
// Phase 1: stage 8 token rows (32KB contiguous) into padded LDS (nt loads).
// Phase 2: gate dots from LDS; shfl_xor reduce over 8 in-wave segments;
//          cross-wave LDS reduce; sigmoid; top-2 -> recs[].
// Phase 3: wave handles 2 tokens: expert dots from LDS x + L2-hot wc;
//          broadcast nt store.
// ---------------------------------------------------------------------------
__global__ __launch_bounds__(256) void fused_kernel(
    const float* __restrict__ x,        // [NTOK, DIN]
    const float* __restrict__ gate_w,   // [DIN, E]
    const float* __restrict__ gate_b,   // [E]
    const float* __restrict__ ebias,    // [E]
    const float* __restrict__ wc,       // [E, K, DIN]
    const float* __restrict__ expert_b, // [E, DOUT]
    float* __restrict__ out_final,      // [NTOK, DOUT]
    float* __restrict__ out_probs,      // [NTOK, E]
    float* __restrict__ out_idx,        // [NTOK, K] as float
    int write_aux)
{
    __shared__ float4 xs[TPB * RS4];    // 32.9 KB padded x tile
    __shared__ float red2[4][TPB][17];  // [wave][tok][e] 2.2 KB
    __shared__ float lgt[TPB][17];      // [tok][e] logits (pre-ebias)
    __shared__ float4 recs[TPB];        // (e0, e1, w0, w1) per token

    const int tid  = threadIdx.x;
    const int wave = tid >> 6;
    const int lane = tid & 63;
    const int blk  = blockIdx.x;

    // ---- Phase 1: stage x tile (8 rows = 2048 float4, contiguous, nt) ----
    const nf4* xg = (const nf4*)(x + (size_t)blk * TPB * DIN_);
#pragma unroll
    for (int k = 0; k < 8; k++) {
        int g = k * 256 + tid;                       // 0..2047, coalesced
        nf4 v = __builtin_nontemporal_load(&xg[g]);
        xs[(g >> 8) * RS4 + (g & 255)] = make_float4(v.x, v.y, v.z, v.w);
    }
    __syncthreads();

    // ---- Phase 2: gate dots. 32 segs x 32 d; 8 segs per wave per token ----
    const int seg = tid >> 3;           // 0..31 (wave w owns segs 8w..8w+7)
    const int tok = tid & 7;            // 0..7
    const float4* xrow = xs + tok * RS4 + seg * 8;
    const float4* gw4  = (const float4*)gate_w;      // row d = 4 float4s

    float acc[NE];
#pragma unroll
    for (int e = 0; e < NE; e++) acc[e] = 0.f;

#pragma unroll
    for (int i = 0; i < 8; i++) {
        float4 xv = xrow[i];
        int d0 = seg * 32 + i * 4;
#pragma unroll
        for (int j = 0; j < 4; j++) {
            int d = d0 + j;
            float xs_ = (j == 0) ? xv.x : (j == 1) ? xv.y : (j == 2) ? xv.z : xv.w;
            float4 g0 = gw4[d * 4 + 0];
            float4 g1 = gw4[d * 4 + 1];
            float4 g2 = gw4[d * 4 + 2];
            float4 g3 = gw4[d * 4 + 3];
            acc[0]  += xs_ * g0.x; acc[1]  += xs_ * g0.y; acc[2]  += xs_ * g0.z; acc[3]  += xs_ * g0.w;
            acc[4]  += xs_ * g1.x; acc[5]  += xs_ * g1.y; acc[6]  += xs_ * g1.z; acc[7]  += xs_ * g1.w;
            acc[8]  += xs_ * g2.x; acc[9]  += xs_ * g2.y; acc[10] += xs_ * g2.z; acc[11] += xs_ * g2.w;
            acc[12] += xs_ * g3.x; acc[13] += xs_ * g3.y; acc[14] += xs_ * g3.z; acc[15] += xs_ * g3.w;
        }
    }

    // in-wave reduce over the wave's 8 segments (lane^8/16/32 flip seg bits)
#pragma unroll
    for (int e = 0; e < NE; e++) {
        acc[e] += __shfl_xor(acc[e], 8);
        acc[e] += __shfl_xor(acc[e], 16);
        acc[e] += __shfl_xor(acc[e], 32);
    }
    // one writer pair per (wave, tok): seg-in-wave q writes experts 2q,2q+1
    {
        const int q = seg & 7;
        red2[wave][tok][q * 2 + 0] = acc[q * 2 + 0];
        red2[wave][tok][q * 2 + 1] = acc[q * 2 + 1];
    }
    __syncthreads();

    // cross-wave reduce + sigmoid + probs write: thread = (rtok, e), tid<128
    if (tid < TPB * NE) {
        const int rtok = tid >> 4;
        const int e    = tid & 15;
        float s = red2[0][rtok][e] + red2[1][rtok][e]
                + red2[2][rtok][e] + red2[3][rtok][e] + gate_b[e];
        if (write_aux)
            out_probs[(size_t)(blk * TPB + rtok) * NE + e] = 1.f / (1.f + expf(-s));
        lgt[rtok][e] = s;
    }
    __syncthreads();

    // top-2 + normalized weights: threads 0..7, one token each
    if (tid < TPB) {
        const int ftok = tid;
        const int gtoken = blk * TPB + ftok;
        float go[NE], logit[NE];
#pragma unroll
        for (int e = 0; e < NE; e++) {
            go[e] = lgt[ftok][e];
            logit[e] = go[e] + ebias[e];
        }
        // stable top-2 (descending; ties -> lower index)
        int i0 = 0;
        for (int e = 1; e < NE; e++) if (logit[e] > logit[i0]) i0 = e;
        int i1 = -1;
        for (int e = 0; e < NE; e++) {
            if (e == i0) continue;
            if (i1 < 0 || logit[e] > logit[i1]) i1 = e;
        }
        float p0 = 1.f / (1.f + expf(-go[i0]));
        float p1 = 1.f / (1.f + expf(-go[i1]));
        float inv = 1.f / (p0 + p1);
        if (write_aux) {
            out_idx[(size_t)gtoken * KK + 0] = (float)i0;
            out_idx[(size_t)gtoken * KK + 1] = (float)i1;
        }
        recs[ftok] = make_float4((float)i0, (float)i1, p0 * inv, p1 * inv);
    }
    __syncthreads();

    // ---- Phase 3: expert dots + broadcast store. Wave w -> tokens 2w,2w+1 ----
#pragma unroll
    for (int it = 0; it < 2; it++) {
        const int lt = wave * 2 + it;
        float4 rec = recs[lt];                       // uniform broadcast read
        int e0 = (int)rec.x;
        int e1 = (int)rec.y;
        const float4* xr = xs + lt * RS4;
        const float4* w0 = (const float4*)(wc + ((size_t)e0 * KK + 0) * DIN_);
        const float4* w1 = (const float4*)(wc + ((size_t)e1 * KK + 1) * DIN_);
        float g0 = 0.f, g1 = 0.f;
#pragma unroll
        for (int i = 0; i < 4; i++) {
            float4 xv = xr[i * 64 + lane];
            float4 a  = w0[i * 64 + lane];
            float4 b  = w1[i * 64 + lane];
            g0 += xv.x * a.x + xv.y * a.y + xv.z * a.z + xv.w * a.w;
            g1 += xv.x * b.x + xv.y * b.y + xv.z * b.z + xv.w * b.w;
        }
#pragma unroll
        for (int m = 32; m >= 1; m >>= 1) {
            g0 += __shfl_xor(g0, m);
            g1 += __shfl_xor(g1, m);
        }
        float f = rec.z * (g0 + expert_b[(size_t)e0 * DOUT_ + 0])
                + rec.w * (g1 + expert_b[(size_t)e1 * DOUT_ + 1]);
        nf4 fv = {f, f, f, f};
        nf4* o4 = (nf4*)(out_final + (size_t)(blk * TPB + lt) * DOUT_);
#pragma unroll
        for (int i = 0; i < 4; i++)
            __builtin_nontemporal_store(fv, &o4[i * 64 + lane]);
    }
}

// ---------------------------------------------------------------------------
extern "C" void kernel_launch(void* const* d_in, const int* in_sizes, int n_in,
                              void* d_out, int out_size, void* d_ws, size_t ws_size,
                              hipStream_t stream) {
    const float* x        = (const float*)d_in[0];
    const float* gate_w   = (const float*)d_in[1];
    const float* gate_b   = (const float*)d_in[2];
    const float* expert_w = (const float*)d_in[3];
    const float* expert_b = (const float*)d_in[4];
    const float* ebias    = (const float*)d_in[5];
    float* out = (float*)d_out;

    float* wc = (float*)d_ws;                             // 128 KB

    float* out_final = out;
    float* out_probs = out + (size_t)NTOK * DOUT_;
    float* out_idx   = out_probs + (size_t)NTOK * NE;
    int write_aux = (out_size >= NTOK * DOUT_ + NTOK * NE + NTOK * KK) ? 1 : 0;

    compact_w_kernel<<<(NE * DIN_ + 255) / 256, 256, 0, stream>>>(expert_w, wc);
    fused_kernel<<<NTOK / TPB, 256, 0, stream>>>(
        x, gate_w, gate_b, ebias, wc, expert_b,
        out_final, out_probs, out_idx, write_aux);
}